// Round 1
// baseline (735.141 us; speedup 1.0000x reference)
//
#include <hip/hip_runtime.h>
#include <math.h>

#define DIM 4096
#define NH 32
#define NKV 8
#define HD 128
#define BATCH 32
#define CL 2176
#define QKV_DIM 6144  // (32 + 2*8) * 128
#define NREP 4

// ---------------------------------------------------------------------------
// Kernel: k-split GEMV-style GEMM partial.  C_part[kc][b][n] = sum over 128 k.
// grid (N/256, 32), block 256.  x is [32][DIM] row-major, w is [DIM][N].
// x-tile transposed into LDS with pad 36 so inner loop reads broadcast b128.
// ---------------------------------------------------------------------------
template<int N>
__global__ void gemm_partial(const float* __restrict__ x, const float* __restrict__ w,
                             float* __restrict__ part) {
    __shared__ float xs[128 * 36];  // xs[kk][b], padded stride 36 (16B-aligned rows)
    const int t = threadIdx.x;
    const int n0 = blockIdx.x * 256;
    const int k0 = blockIdx.y * 128;

    // load x tile: 32 batches x 128 k = 4096 floats, coalesced
    for (int i = 0; i < 16; ++i) {
        int e = t + i * 256;
        int b = e >> 7;      // /128
        int kk = e & 127;
        xs[kk * 36 + b] = x[(size_t)b * DIM + k0 + kk];
    }
    __syncthreads();

    float acc[32];
#pragma unroll
    for (int b = 0; b < 32; ++b) acc[b] = 0.f;

    const float* wp = w + (size_t)k0 * N + n0 + t;
    for (int kk = 0; kk < 128; ++kk) {
        float wv = wp[(size_t)kk * N];
        const float4* xr = (const float4*)&xs[kk * 36];
#pragma unroll
        for (int b4 = 0; b4 < 8; ++b4) {
            float4 xv = xr[b4];
            acc[b4 * 4 + 0] += xv.x * wv;
            acc[b4 * 4 + 1] += xv.y * wv;
            acc[b4 * 4 + 2] += xv.z * wv;
            acc[b4 * 4 + 3] += xv.w * wv;
        }
    }

    float* pp = part + (size_t)blockIdx.y * 32 * N + n0 + t;
#pragma unroll
    for (int b = 0; b < 32; ++b) pp[(size_t)b * N] = acc[b];
}

// ---------------------------------------------------------------------------
// Kernel: reduce QKV partials + RoPE.  grid (32, 48), block 128.
// fin layout: [b][48][128]; heads 0..31 = q(roped), 32..39 = k(roped), 40..47 = v
// ---------------------------------------------------------------------------
__global__ void qkv_finish(const float* __restrict__ part, const int* __restrict__ sp_p,
                           float* __restrict__ fin) {
    const int b = blockIdx.x, h = blockIdx.y, d = threadIdx.x;
    const int sp = *sp_p;
    const int col = h * 128 + d;

    float s = 0.f;
    for (int kc = 0; kc < 32; ++kc)
        s += part[(size_t)kc * 32 * QKV_DIM + (size_t)b * QKV_DIM + col];

    __shared__ float v[128];
    float outv = s;
    if (h < 40) {  // q and k heads get RoPE
        v[d] = s;
        __syncthreads();
        int j = d & 63;
        float inv_freq = powf(10000.0f, -(float)(2 * j) / 128.0f);
        float ang = (float)sp * inv_freq;
        float c = cosf(ang), sn = sinf(ang);
        float rot = (d < 64) ? -v[d + 64] : v[d - 64];
        outv = s * c + rot * sn;
    }
    fin[((size_t)b * 48 + h) * 128 + d] = outv;
}

// ---------------------------------------------------------------------------
// Kernel: QK^T scores.  grid (256 bg, 2 s-halves), block 1024 (16 waves).
// Each wave: 2 rows / iter; lane holds float4 of the K row; 5-step shfl_xor
// reduce within each 32-lane half.  scores layout [bg][s][4 heads].
// ---------------------------------------------------------------------------
__global__ void attn_scores(const float* __restrict__ fin, const float* __restrict__ cache_k,
                            const int* __restrict__ sp_p, float* __restrict__ scores) {
    const int bg = blockIdx.x;
    const int b = bg >> 3, g = bg & 7;
    const int sp = *sp_p;
    const int t = threadIdx.x;
    const int w = t >> 6, lane = t & 63, sl = lane & 31, half = lane >> 5;

    float4 qf[4];
#pragma unroll
    for (int h = 0; h < 4; ++h)
        qf[h] = *(const float4*)(fin + ((size_t)b * 48 + g * 4 + h) * 128 + sl * 4);

    const float scale = 0.08838834764831845f;  // 1/sqrt(128)
    const float* kbase = cache_k + ((size_t)b * NKV + g) * CL * HD;
    const float* knew = fin + ((size_t)b * 48 + 32 + g) * 128;

    const int s_begin = blockIdx.y * 1088;          // 1088 = CL/2, multiple of 32
    const int s_end = s_begin + 1088;

    for (int i = s_begin + w * 2; i < s_end; i += 32) {
        int s = i + half;
        const float* krow = (s == sp) ? knew : (kbase + (size_t)s * HD);
        float4 kv = *(const float4*)(krow + sl * 4);

        float p[4];
#pragma unroll
        for (int h = 0; h < 4; ++h)
            p[h] = qf[h].x * kv.x + qf[h].y * kv.y + qf[h].z * kv.z + qf[h].w * kv.w;

#pragma unroll
        for (int off = 1; off < 32; off <<= 1) {
#pragma unroll
            for (int h = 0; h < 4; ++h) p[h] += __shfl_xor(p[h], off);
        }

        if (sl == 0) {
            bool valid = (s <= sp);
            float4 sc;
            sc.x = valid ? p[0] * scale : -1e9f;
            sc.y = valid ? p[1] * scale : -1e9f;
            sc.z = valid ? p[2] * scale : -1e9f;
            sc.w = valid ? p[3] * scale : -1e9f;
            *(float4*)(scores + ((size_t)bg * CL + s) * 4) = sc;
        }
    }
}

// ---------------------------------------------------------------------------
// Kernel: softmax in place over s.  grid (256 bg, 4 h), block 256.
// ---------------------------------------------------------------------------
__global__ void softmax_k(float* __restrict__ scores) {
    const int bg = blockIdx.x, h = blockIdx.y, t = threadIdx.x;
    float* sb = scores + (size_t)bg * CL * 4 + h;

    float vals[9];
    float m = -1e30f;
#pragma unroll
    for (int i = 0; i < 9; ++i) {
        int s = t + i * 256;
        vals[i] = (s < CL) ? sb[(size_t)s * 4] : -1e30f;
        m = fmaxf(m, vals[i]);
    }
#pragma unroll
    for (int off = 1; off < 64; off <<= 1) m = fmaxf(m, __shfl_xor(m, off));
    __shared__ float redm[4];
    const int w = t >> 6, lane = t & 63;
    if (lane == 0) redm[w] = m;
    __syncthreads();
    m = fmaxf(fmaxf(redm[0], redm[1]), fmaxf(redm[2], redm[3]));

    float l = 0.f;
#pragma unroll
    for (int i = 0; i < 9; ++i) {
        float e = expf(vals[i] - m);  // masked (-1e9/-1e30) underflow to exactly 0
        vals[i] = e;
        l += e;
    }
#pragma unroll
    for (int off = 1; off < 64; off <<= 1) l += __shfl_xor(l, off);
    __shared__ float redl[4];
    if (lane == 0) redl[w] = l;
    __syncthreads();
    l = redl[0] + redl[1] + redl[2] + redl[3];

    float inv = 1.f / l;
#pragma unroll
    for (int i = 0; i < 9; ++i) {
        int s = t + i * 256;
        if (s < CL) sb[(size_t)s * 4] = vals[i] * inv;
    }
}

// ---------------------------------------------------------------------------
// Kernel: P @ V.  grid 256 (bg), block 1024.  32 lane-groups stride over s.
// attn layout [b][DIM] with col = (g*4+h)*128 + d.
// ---------------------------------------------------------------------------
__global__ void attn_pv(const float* __restrict__ scores, const float* __restrict__ cache_v,
                        const float* __restrict__ fin, const int* __restrict__ sp_p,
                        float* __restrict__ attn) {
    const int bg = blockIdx.x;
    const int b = bg >> 3, g = bg & 7;
    const int sp = *sp_p;
    const int t = threadIdx.x;
    const int grp = t >> 5, sl = t & 31;

    const float* vbase = cache_v + ((size_t)b * NKV + g) * CL * HD;
    const float* vnew = fin + ((size_t)b * 48 + 40 + g) * 128;
    const float* pb = scores + (size_t)bg * CL * 4;

    float o[4][4];
#pragma unroll
    for (int h = 0; h < 4; ++h)
#pragma unroll
        for (int c = 0; c < 4; ++c) o[h][c] = 0.f;

    for (int s = grp; s < CL; s += 32) {
        const float* vrow = (s == sp) ? vnew : (vbase + (size_t)s * HD);
        float4 vv = *(const float4*)(vrow + sl * 4);
        float4 pp = *(const float4*)(pb + (size_t)s * 4);  // broadcast within group
        o[0][0] += pp.x * vv.x; o[0][1] += pp.x * vv.y; o[0][2] += pp.x * vv.z; o[0][3] += pp.x * vv.w;
        o[1][0] += pp.y * vv.x; o[1][1] += pp.y * vv.y; o[1][2] += pp.y * vv.z; o[1][3] += pp.y * vv.w;
        o[2][0] += pp.z * vv.x; o[2][1] += pp.z * vv.y; o[2][2] += pp.z * vv.z; o[2][3] += pp.z * vv.w;
        o[3][0] += pp.w * vv.x; o[3][1] += pp.w * vv.y; o[3][2] += pp.w * vv.z; o[3][3] += pp.w * vv.w;
    }

    __shared__ float red[32 * 512];
#pragma unroll
    for (int h = 0; h < 4; ++h)
        *(float4*)&red[grp * 512 + h * 128 + sl * 4] = make_float4(o[h][0], o[h][1], o[h][2], o[h][3]);
    __syncthreads();

    for (int step = 16; step >= 1; step >>= 1) {
        if (grp < step) {
#pragma unroll
            for (int i = 0; i < 16; ++i) {
                int j = sl + i * 32;
                red[grp * 512 + j] += red[(grp + step) * 512 + j];
            }
        }
        __syncthreads();
    }

    if (t < 512) {
        int h = t >> 7, d = t & 127;
        attn[(size_t)b * DIM + (g * 4 + h) * 128 + d] = red[h * 128 + d];
    }
}

// ---------------------------------------------------------------------------
// Kernel: final reduce of output-projection partials.  grid 512, block 256.
// ---------------------------------------------------------------------------
__global__ void out_reduce(const float* __restrict__ part, float* __restrict__ out) {
    const int e = blockIdx.x * 256 + threadIdx.x;
    float s = 0.f;
    for (int kc = 0; kc < 32; ++kc) s += part[(size_t)kc * 32 * DIM + e];
    out[e] = s;
}

// ---------------------------------------------------------------------------
extern "C" void kernel_launch(void* const* d_in, const int* in_sizes, int n_in,
                              void* d_out, int out_size, void* d_ws, size_t ws_size,
                              hipStream_t stream) {
    const float* x       = (const float*)d_in[0];
    const float* wqkv    = (const float*)d_in[1];
    const float* wo      = (const float*)d_in[2];
    const float* cache_k = (const float*)d_in[3];
    const float* cache_v = (const float*)d_in[4];
    const int*   sp      = (const int*)d_in[5];
    float* out = (float*)d_out;
    float* ws  = (float*)d_ws;

    // workspace layout (floats)
    float* part1  = ws;                       // 32*32*6144   = 6,291,456
    float* fin    = part1 + 6291456;          // 32*48*128    =   196,608
    float* scores = fin + 196608;             // 256*2176*4   = 2,228,224
    float* attn   = scores + 2228224;         // 32*4096      =   131,072
    float* part2  = attn + 131072;            // 32*32*4096   = 4,194,304
    // total 13,041,664 floats = 52.2 MB

    gemm_partial<QKV_DIM><<<dim3(24, 32), 256, 0, stream>>>(x, wqkv, part1);
    qkv_finish<<<dim3(32, 48), 128, 0, stream>>>(part1, sp, fin);
    attn_scores<<<dim3(256, 2), 1024, 0, stream>>>(fin, cache_k, sp, scores);
    softmax_k<<<dim3(256, 4), 256, 0, stream>>>(scores);
    attn_pv<<<256, 1024, 0, stream>>>(scores, cache_v, fin, sp, attn);
    gemm_partial<DIM><<<dim3(16, 32), 256, 0, stream>>>(attn, wo, part2);
    out_reduce<<<512, 256, 0, stream>>>(part2, out);
}